// Round 7
// baseline (2080.272 us; speedup 1.0000x reference)
//
#include <hip/hip_runtime.h>
#include <hip/hip_fp16.h>

// RNN h_{t+1} = tanh(x_t*W_ih + b_ih + b_hh + h_t @ W_hh^T), T=1024, B=64, H=512.
//
// Round 7: single CU per batch (64 WGs x 512 thr). Three-pipe balance:
//  - VALU: 256 v_dot2_f32_f16/thread/step on weights held in 12 NAMED uint16
//    ext_vector registers (192 VGPRs). No arrays, no address casts -> SROA-safe
//    (round 3/6 failure: reinterpret_cast of local arrays forced scratch).
//  - LDS:  h (padded 144B/group stride -> the 8 broadcast addrs hit 8 distinct
//    bank quads, conflict-free) + 4 tail chunks wl[4][512] (per-wave contiguous).
//  - VMEM: 12 tail chunks/thread streamed from ws each step (96KB/CU/step,
//    L2-resident, h-independent -> prefetchable). Opaque per-iter zero offset
//    stops LICM from hoisting them into registers.
//  - Reduce over 8 k-groups: DPP row_ror:8 (VALU) + shfl_xor 16/32.
//  - Thread (w=tid>>6, g=lane>>3, i=lane&7): rows j_m=64w+8m+i, k in [64g,64g+64).
//    After all-reduce each lane publishes row m=g -> jp = 64w+lane.
// One __syncthreads per step. No cross-WG traffic, no atomics, no polling.

#define BB 64
#define TT 1024
#define HH 512

typedef _Float16 half2_t __attribute__((ext_vector_type(2)));
typedef unsigned uint16v __attribute__((ext_vector_type(16)));

__device__ __forceinline__ float dot2f(unsigned h, unsigned w, float acc) {
    return __builtin_amdgcn_fdot2(__builtin_bit_cast(half2_t, h),
                                  __builtin_bit_cast(half2_t, w), acc, false);
}
__device__ __forceinline__ float fast_tanh(float z) {
    float e = __expf(2.0f * z);
    return fmaf(-2.0f, __builtin_amdgcn_rcpf(e + 1.0f), 1.0f);
}
__device__ __forceinline__ unsigned pack_h2(float a, float b) {
    return __builtin_bit_cast(unsigned, __floats2half2_rn(a, b));
}
// lane L += lane L^8 (within 16-lane DPP row, ror:8 == xor 8) - pure VALU
__device__ __forceinline__ float xor8_add(float a) {
    int y = __builtin_amdgcn_update_dpp(0, __builtin_bit_cast(int, a),
                                        0x128, 0xF, 0xF, false);
    return a + __builtin_bit_cast(float, y);
}

#define DOT4(u, wv, A)                                                   \
    A = dot2f((u).x, (wv).x, A); A = dot2f((u).y, (wv).y, A);            \
    A = dot2f((u).z, (wv).z, A); A = dot2f((u).w, (wv).w, A);

#define DOTQ(u, Qv, A0, A1, A2, A3)                                      \
    A0 = dot2f((u).x, Qv[0],  A0); A0 = dot2f((u).y, Qv[1],  A0);        \
    A0 = dot2f((u).z, Qv[2],  A0); A0 = dot2f((u).w, Qv[3],  A0);        \
    A1 = dot2f((u).x, Qv[4],  A1); A1 = dot2f((u).y, Qv[5],  A1);        \
    A1 = dot2f((u).z, Qv[6],  A1); A1 = dot2f((u).w, Qv[7],  A1);        \
    A2 = dot2f((u).x, Qv[8],  A2); A2 = dot2f((u).y, Qv[9],  A2);        \
    A2 = dot2f((u).z, Qv[10], A2); A2 = dot2f((u).w, Qv[11], A2);        \
    A3 = dot2f((u).x, Qv[12], A3); A3 = dot2f((u).y, Qv[13], A3);        \
    A3 = dot2f((u).z, Qv[14], A3); A3 = dot2f((u).w, Qv[15], A3);

#define PK4(Rp, c, e) pack_h2((Rp)[8*(c)+2*(e)], (Rp)[8*(c)+2*(e)+1])
#define PKROW(Qv, base, Rp, c)                                           \
    Qv[(base)+0] = PK4(Rp, c, 0); Qv[(base)+1] = PK4(Rp, c, 1);          \
    Qv[(base)+2] = PK4(Rp, c, 2); Qv[(base)+3] = PK4(Rp, c, 3);
#define FILLQ(Qa, Qb, c)                                                 \
    PKROW(Qa, 0, r0, c) PKROW(Qa, 4, r1, c)                              \
    PKROW(Qa, 8, r2, c) PKROW(Qa, 12, r3, c)                             \
    PKROW(Qb, 0, r4, c) PKROW(Qb, 4, r5, c)                              \
    PKROW(Qb, 8, r6, c) PKROW(Qb, 12, r7, c)
#define MK4(Rp, c) make_uint4(PK4(Rp,c,0), PK4(Rp,c,1), PK4(Rp,c,2), PK4(Rp,c,3))

__launch_bounds__(512, 2)
__global__ void rnn_cu2(const float* __restrict__ x,      // [B,T]
                        const float* __restrict__ W_ih,   // [H]
                        const float* __restrict__ W_hh,   // [H,H]
                        const float* __restrict__ b_ih,   // [H]
                        const float* __restrict__ b_hh,   // [H]
                        const float* __restrict__ W_out,  // [H]
                        const float* __restrict__ b_out,  // [1]
                        float* __restrict__ out,          // [64 + B*H]
                        uint4* __restrict__ wsT)          // [12][512]
{
    const int b    = blockIdx.x;
    const int tid  = threadIdx.x;
    const int w    = tid >> 6;
    const int lane = tid & 63;
    const int g    = lane >> 3;     // k-group: halves [64g, 64g+64)
    const int i    = lane & 7;

    __shared__ float xrow[TT];                               // 4KB
    __shared__ __align__(16) unsigned char hbuf[2][8 * 144]; // padded h, 2.25KB
    __shared__ __align__(16) uint4 wl[4][512];               // LDS tail, 32KB

    for (int s = tid; s < TT; s += 512) xrow[s] = x[b * TT + s];

    // ---- weight residency: rows j_m = 64w + 8m + i over halves [64g, 64g+64)
    const float* r0 = W_hh + (size_t)(64*w + 8*0 + i) * HH + 64*g;
    const float* r1 = W_hh + (size_t)(64*w + 8*1 + i) * HH + 64*g;
    const float* r2 = W_hh + (size_t)(64*w + 8*2 + i) * HH + 64*g;
    const float* r3 = W_hh + (size_t)(64*w + 8*3 + i) * HH + 64*g;
    const float* r4 = W_hh + (size_t)(64*w + 8*4 + i) * HH + 64*g;
    const float* r5 = W_hh + (size_t)(64*w + 8*5 + i) * HH + 64*g;
    const float* r6 = W_hh + (size_t)(64*w + 8*6 + i) * HH + 64*g;
    const float* r7 = W_hh + (size_t)(64*w + 8*7 + i) * HH + 64*g;

    // chunks 0..5 (halves 0..47 of window) -> named vector registers
    uint16v Qa0, Qb0, Qa1, Qb1, Qa2, Qb2, Qa3, Qb3, Qa4, Qb4, Qa5, Qb5;
    FILLQ(Qa0, Qb0, 0) FILLQ(Qa1, Qb1, 1) FILLQ(Qa2, Qb2, 2)
    FILLQ(Qa3, Qb3, 3) FILLQ(Qa4, Qb4, 4) FILLQ(Qa5, Qb5, 5)

    // chunk 6 rows 0-3 -> LDS tail
    wl[0][tid] = MK4(r0, 6);
    wl[1][tid] = MK4(r1, 6);
    wl[2][tid] = MK4(r2, 6);
    wl[3][tid] = MK4(r3, 6);

    // chunk 7 rows 0-7 and chunk 6 rows 4-7 -> ws (VMEM stream, identical
    // values written by every block: benign same-value races, self-read only)
    wsT[ 0*512 + tid] = MK4(r0, 7);
    wsT[ 1*512 + tid] = MK4(r1, 7);
    wsT[ 2*512 + tid] = MK4(r2, 7);
    wsT[ 3*512 + tid] = MK4(r3, 7);
    wsT[ 4*512 + tid] = MK4(r4, 7);
    wsT[ 5*512 + tid] = MK4(r5, 7);
    wsT[ 6*512 + tid] = MK4(r6, 7);
    wsT[ 7*512 + tid] = MK4(r7, 7);
    wsT[ 8*512 + tid] = MK4(r4, 6);
    wsT[ 9*512 + tid] = MK4(r5, 6);
    wsT[10*512 + tid] = MK4(r6, 6);
    wsT[11*512 + tid] = MK4(r7, 6);

    // publisher constants: this lane publishes row jp = 64w + 8g + i = 64w+lane
    const int jp = 64 * w + lane;
    const float wih  = W_ih[jp];
    const float bias = b_ih[jp] + b_hh[jp];

    __syncthreads();   // xrow + wl visible

#pragma unroll 1
    for (int t = 0; t < TT; ++t) {
        const int par = t & 1;
        float a0 = 0.f, a1 = 0.f, a2 = 0.f, a3 = 0.f;
        float a4 = 0.f, a5 = 0.f, a6 = 0.f, a7 = 0.f;
        if (t > 0) {
            // opaque zero: keeps the tail loads inside the loop (no LICM) while
            // letting the compiler schedule/waitcnt them normally
            int zr; asm volatile("v_mov_b32 %0, 0" : "=v"(zr));
            const uint4* wp = wsT + tid + zr;
            const uint4 T0  = wp[ 0*512], T1  = wp[ 1*512], T2  = wp[ 2*512];
            const uint4 T3  = wp[ 3*512], T4  = wp[ 4*512], T5  = wp[ 5*512];
            const uint4 T6  = wp[ 6*512], T7  = wp[ 7*512], T8  = wp[ 8*512];
            const uint4 T9  = wp[ 9*512], T10 = wp[10*512], T11 = wp[11*512];

            const unsigned char* hB = &hbuf[par][0] + g * 144;
            const uint4 u0 = *(const uint4*)(hB +  0);
            DOTQ(u0, Qa0, a0, a1, a2, a3) DOTQ(u0, Qb0, a4, a5, a6, a7)
            const uint4 u1 = *(const uint4*)(hB + 16);
            DOTQ(u1, Qa1, a0, a1, a2, a3) DOTQ(u1, Qb1, a4, a5, a6, a7)
            const uint4 u2 = *(const uint4*)(hB + 32);
            DOTQ(u2, Qa2, a0, a1, a2, a3) DOTQ(u2, Qb2, a4, a5, a6, a7)
            const uint4 u3 = *(const uint4*)(hB + 48);
            DOTQ(u3, Qa3, a0, a1, a2, a3) DOTQ(u3, Qb3, a4, a5, a6, a7)
            const uint4 u4 = *(const uint4*)(hB + 64);
            DOTQ(u4, Qa4, a0, a1, a2, a3) DOTQ(u4, Qb4, a4, a5, a6, a7)
            const uint4 u5 = *(const uint4*)(hB + 80);
            DOTQ(u5, Qa5, a0, a1, a2, a3) DOTQ(u5, Qb5, a4, a5, a6, a7)

            // tail chunk 6: rows 0-3 from LDS, rows 4-7 from VMEM
            const uint4 u6 = *(const uint4*)(hB + 96);
            const uint4 l0 = wl[0][tid + zr], l1 = wl[1][tid + zr];
            const uint4 l2 = wl[2][tid + zr], l3 = wl[3][tid + zr];
            DOT4(u6, l0, a0) DOT4(u6, l1, a1) DOT4(u6, l2, a2) DOT4(u6, l3, a3)
            DOT4(u6, T8, a4) DOT4(u6, T9, a5) DOT4(u6, T10, a6) DOT4(u6, T11, a7)
            // tail chunk 7: rows 0-7 from VMEM
            const uint4 u7 = *(const uint4*)(hB + 112);
            DOT4(u7, T0, a0) DOT4(u7, T1, a1) DOT4(u7, T2, a2) DOT4(u7, T3, a3)
            DOT4(u7, T4, a4) DOT4(u7, T5, a5) DOT4(u7, T6, a6) DOT4(u7, T7, a7)
        }
        // ---- all-reduce over the 8 k-groups (lanes i, i+8, ..., i+56)
        a0 = xor8_add(a0); a0 += __shfl_xor(a0, 16, 64); a0 += __shfl_xor(a0, 32, 64);
        a1 = xor8_add(a1); a1 += __shfl_xor(a1, 16, 64); a1 += __shfl_xor(a1, 32, 64);
        a2 = xor8_add(a2); a2 += __shfl_xor(a2, 16, 64); a2 += __shfl_xor(a2, 32, 64);
        a3 = xor8_add(a3); a3 += __shfl_xor(a3, 16, 64); a3 += __shfl_xor(a3, 32, 64);
        a4 = xor8_add(a4); a4 += __shfl_xor(a4, 16, 64); a4 += __shfl_xor(a4, 32, 64);
        a5 = xor8_add(a5); a5 += __shfl_xor(a5, 16, 64); a5 += __shfl_xor(a5, 32, 64);
        a6 = xor8_add(a6); a6 += __shfl_xor(a6, 16, 64); a6 += __shfl_xor(a6, 32, 64);
        a7 = xor8_add(a7); a7 += __shfl_xor(a7, 16, 64); a7 += __shfl_xor(a7, 32, 64);

        // this lane publishes row m = g
        const float v = (g & 4) ? ((g & 2) ? ((g & 1) ? a7 : a6) : ((g & 1) ? a5 : a4))
                                : ((g & 2) ? ((g & 1) ? a3 : a2) : ((g & 1) ? a1 : a0));
        const float z = fmaf(xrow[t], wih, v + bias);
        const float h = fast_tanh(z);
        *(unsigned short*)(&hbuf[par ^ 1][w * 144 + lane * 2]) =
            __builtin_bit_cast(unsigned short, (_Float16)h);
        if (t == TT - 1) out[64 + b * HH + jp] = h;
        __syncthreads();   // the ONLY barrier per step
    }

    // ---- epilogue: wave 0 computes out[b] = h_last . W_out + b_out
    if (w == 0) {
        const uint4 hv =
            *(const uint4*)(&hbuf[0][(lane >> 3) * 144 + (lane & 7) * 16]);
        const float4 w0 = reinterpret_cast<const float4*>(W_out)[2 * lane + 0];
        const float4 w1 = reinterpret_cast<const float4*>(W_out)[2 * lane + 1];
        float s = 0.f;
        __half2 p;
        p = __builtin_bit_cast(__half2, hv.x);
        s = fmaf(__low2float(p), w0.x, s); s = fmaf(__high2float(p), w0.y, s);
        p = __builtin_bit_cast(__half2, hv.y);
        s = fmaf(__low2float(p), w0.z, s); s = fmaf(__high2float(p), w0.w, s);
        p = __builtin_bit_cast(__half2, hv.z);
        s = fmaf(__low2float(p), w1.x, s); s = fmaf(__high2float(p), w1.y, s);
        p = __builtin_bit_cast(__half2, hv.w);
        s = fmaf(__low2float(p), w1.z, s); s = fmaf(__high2float(p), w1.w, s);
#pragma unroll
        for (int off = 32; off; off >>= 1) s += __shfl_down(s, off, 64);
        if (lane == 0) out[b] = s + b_out[0];
    }
}

extern "C" void kernel_launch(void* const* d_in, const int* in_sizes, int n_in,
                              void* d_out, int out_size, void* d_ws, size_t ws_size,
                              hipStream_t stream) {
    const float* x     = (const float*)d_in[0];  // inputs [B,T,1]
    // d_in[1] = state (ignored; reference uses zero initial hidden state)
    const float* W_ih  = (const float*)d_in[2];
    const float* W_hh  = (const float*)d_in[3];
    const float* b_ih  = (const float*)d_in[4];
    const float* b_hh  = (const float*)d_in[5];
    const float* W_out = (const float*)d_in[6];
    const float* b_out = (const float*)d_in[7];

    uint4* wsT = (uint4*)d_ws;   // 12*512*16B = 96KB packed fp16 weight tails

    rnn_cu2<<<dim3(BB), dim3(512), 0, stream>>>(
        x, W_ih, W_hh, b_ih, b_hh, W_out, b_out, (float*)d_out, wsT);
}

// Round 8
// 1814.756 us; speedup vs baseline: 1.1463x; 1.1463x over previous
//
#include <hip/hip_runtime.h>
#include <hip/hip_fp16.h>

// RNN h_{t+1} = tanh(x_t*W_ih + b_ih + b_hh + h_t @ W_hh^T), T=1024, B=64, H=512.
//
// Round 8: single CU per batch (64 WGs x 512 thr). The R3/R6/R7 failures were
// all one mechanism: 512-thr WGs get arch-VGPR-capped at 128 and weights land
// in AGPRs (v_accvgpr_read per use). Fix: amdgpu_waves_per_eu(2,2) pins the
// budget to 256 arch VGPRs.
//  - Thread (w=tid>>6, i=lane&7, g=(lane>>3)&7): rows j_m = 64w+8m+i (m=0..7),
//    k-window halves [64g, 64g+64) = 8 uint4 chunks/row.
//  - Chunks 0-5 -> 48 NAMED uint4s (192 VGPRs). Chunk 6 -> LDS wl[m][tid]
//    (contiguous per wave, conflict-free). Chunk 7 -> ws/L2 stream (64KB/step,
//    separate pipe, latency hidden under the 192 register-dots).
//  - sched_barrier(0) fences keep T and L live ranges disjoint (peak ~246 regs).
//  - h fp16 in LDS, windows padded to 144B -> 8 broadcast addrs hit 8 distinct
//    bank quads (conflict-free b128 broadcast reads).
//  - Reduce over 8 windows: DPP row_ror:8 (xor8) + v_permlane32_swap (xor32,
//    VALU) + shfl_xor(16). Each lane then owns exactly ONE output row.
// One __syncthreads per step. No cross-WG traffic (proven >=2000cy/step).

#define BB 64
#define TT 1024
#define HH 512

typedef _Float16 half2_t __attribute__((ext_vector_type(2)));

__device__ __forceinline__ float dot2f(unsigned h, unsigned w, float acc) {
    return __builtin_amdgcn_fdot2(__builtin_bit_cast(half2_t, h),
                                  __builtin_bit_cast(half2_t, w), acc, false);
}
__device__ __forceinline__ float fast_tanh(float z) {
    float e = __expf(2.0f * z);
    return fmaf(-2.0f, __builtin_amdgcn_rcpf(e + 1.0f), 1.0f);
}
__device__ __forceinline__ unsigned pack_h2(float a, float b) {
    return __builtin_bit_cast(unsigned, __floats2half2_rn(a, b));
}
__device__ __forceinline__ uint4 pk4(float4 a, float4 b) {
    return make_uint4(pack_h2(a.x, a.y), pack_h2(a.z, a.w),
                      pack_h2(b.x, b.y), pack_h2(b.z, b.w));
}
// lane l += lane l^8 (row_ror:8 within each 16-lane row == xor 8)
__device__ __forceinline__ float xor8_add(float a) {
    int y = __builtin_amdgcn_update_dpp(0, __builtin_bit_cast(int, a),
                                        0x128, 0xF, 0xF, false);
    return a + __builtin_bit_cast(float, y);
}

#define DOT4(u, wv, A) { A = dot2f((u).x,(wv).x,A); A = dot2f((u).y,(wv).y,A); \
                         A = dot2f((u).z,(wv).z,A); A = dot2f((u).w,(wv).w,A); }
#define DOTC(u, C) DOT4(u, W0##C, a0) DOT4(u, W1##C, a1) DOT4(u, W2##C, a2) \
                   DOT4(u, W3##C, a3) DOT4(u, W4##C, a4) DOT4(u, W5##C, a5) \
                   DOT4(u, W6##C, a6) DOT4(u, W7##C, a7)

__attribute__((amdgpu_flat_work_group_size(512, 512), amdgpu_waves_per_eu(2, 2)))
__global__ void rnn_cu3(const float* __restrict__ x,      // [B,T]
                        const float* __restrict__ W_ih,   // [H]
                        const float* __restrict__ W_hh,   // [H,H]
                        const float* __restrict__ b_ih,   // [H]
                        const float* __restrict__ b_hh,   // [H]
                        const float* __restrict__ W_out,  // [H]
                        const float* __restrict__ b_out,  // [1]
                        float* __restrict__ out,          // [64 + B*H]
                        uint4* __restrict__ wsT)          // [8][512] chunk-7 tails
{
    const int b    = blockIdx.x;
    const int tid  = threadIdx.x;
    const int w    = tid >> 6;
    const int lane = tid & 63;
    const int i    = lane & 7;
    const int g    = (lane >> 3) & 7;   // k-window: halves [64g, 64g+64)

    __shared__ float xrow[TT];                            // 4KB
    __shared__ __align__(16) unsigned char hbuf[2][1152]; // 8 windows x 144B, dbuf
    __shared__ __align__(16) uint4 wl[8][512];            // chunk-6 tails, 64KB

    for (int s = tid; s < TT; s += 512) xrow[s] = x[b * TT + s];

#define ROWP(M) const float4* rp##M = reinterpret_cast<const float4*>( \
        W_hh + (size_t)(64 * w + 8 * M + i) * HH + 64 * g);
    ROWP(0) ROWP(1) ROWP(2) ROWP(3) ROWP(4) ROWP(5) ROWP(6) ROWP(7)

#define DECLW(M) \
    uint4 W##M##0 = pk4(rp##M[0],  rp##M[1]);  \
    uint4 W##M##1 = pk4(rp##M[2],  rp##M[3]);  \
    uint4 W##M##2 = pk4(rp##M[4],  rp##M[5]);  \
    uint4 W##M##3 = pk4(rp##M[6],  rp##M[7]);  \
    uint4 W##M##4 = pk4(rp##M[8],  rp##M[9]);  \
    uint4 W##M##5 = pk4(rp##M[10], rp##M[11]); \
    wl[M][tid]         = pk4(rp##M[12], rp##M[13]); \
    wsT[M * 512 + tid] = pk4(rp##M[14], rp##M[15]);
    DECLW(0) DECLW(1) DECLW(2) DECLW(3) DECLW(4) DECLW(5) DECLW(6) DECLW(7)

    // each lane owns ONE output row: ro = ((lane>>3)&3) + 4*(lane>>5)
    const int ro = ((lane >> 3) & 3) + 4 * (lane >> 5);
    const int jp = 64 * w + 8 * ro + i;
    const float wih  = W_ih[jp];
    const float bias = b_ih[jp] + b_hh[jp];
    const int hslot  = 8 * ro + i;          // slot within this wave's window

    __syncthreads();   // xrow + wl visible (wsT is self-read only)

#pragma unroll 1
    for (int t = 0; t < TT; ++t) {
        const int par = t & 1;
        float a0 = 0.f, a1 = 0.f, a2 = 0.f, a3 = 0.f;
        float a4 = 0.f, a5 = 0.f, a6 = 0.f, a7 = 0.f;
        if (t > 0) {
            int zr; asm volatile("v_mov_b32 %0, 0" : "=v"(zr));  // defeat LICM
            const uint4* tp = wsT + tid + zr;
            const uint4 T0 = tp[0*512], T1 = tp[1*512], T2 = tp[2*512], T3 = tp[3*512];
            const uint4 T4 = tp[4*512], T5 = tp[5*512], T6 = tp[6*512], T7 = tp[7*512];
            const uint4* hp = reinterpret_cast<const uint4*>(&hbuf[par][g * 144]);
            uint4 u;
            u = hp[0]; DOTC(u, 0)
            __builtin_amdgcn_sched_barrier(0);
            u = hp[1]; DOTC(u, 1)
            __builtin_amdgcn_sched_barrier(0);
            u = hp[2]; DOTC(u, 2)
            __builtin_amdgcn_sched_barrier(0);
            u = hp[3]; DOTC(u, 3)
            __builtin_amdgcn_sched_barrier(0);
            u = hp[4]; DOTC(u, 4)
            __builtin_amdgcn_sched_barrier(0);
            u = hp[5]; DOTC(u, 5)
            __builtin_amdgcn_sched_barrier(0);
            // chunk 7 from VMEM regs (T live range ends here)
            u = hp[7];
            DOT4(u, T0, a0) DOT4(u, T1, a1) DOT4(u, T2, a2) DOT4(u, T3, a3)
            DOT4(u, T4, a4) DOT4(u, T5, a5) DOT4(u, T6, a6) DOT4(u, T7, a7)
            __builtin_amdgcn_sched_barrier(0);
            // chunk 6 from LDS (L loads start only after T died)
            const uint4 L0 = wl[0][tid+zr], L1 = wl[1][tid+zr];
            const uint4 L2 = wl[2][tid+zr], L3 = wl[3][tid+zr];
            const uint4 L4 = wl[4][tid+zr], L5 = wl[5][tid+zr];
            const uint4 L6 = wl[6][tid+zr], L7 = wl[7][tid+zr];
            u = hp[6];
            DOT4(u, L0, a0) DOT4(u, L1, a1) DOT4(u, L2, a2) DOT4(u, L3, a3)
            DOT4(u, L4, a4) DOT4(u, L5, a5) DOT4(u, L6, a6) DOT4(u, L7, a7)
        }
        // ---- reduce over 8 k-windows (lane bits 3,4,5) ----
        a0 = xor8_add(a0); a1 = xor8_add(a1); a2 = xor8_add(a2); a3 = xor8_add(a3);
        a4 = xor8_add(a4); a5 = xor8_add(a5); a6 = xor8_add(a6); a7 = xor8_add(a7);
        // xor32 via permlane32_swap: q_m = row m (lanes<32) / row m+4 (lanes>=32)
        asm volatile("v_permlane32_swap_b32 %0, %1" : "+v"(a0), "+v"(a4));
        asm volatile("v_permlane32_swap_b32 %0, %1" : "+v"(a1), "+v"(a5));
        asm volatile("v_permlane32_swap_b32 %0, %1" : "+v"(a2), "+v"(a6));
        asm volatile("v_permlane32_swap_b32 %0, %1" : "+v"(a3), "+v"(a7));
        float q0 = a0 + a4, q1 = a1 + a5, q2 = a2 + a6, q3 = a3 + a7;
        // xor16
        q0 += __shfl_xor(q0, 16, 64);
        q1 += __shfl_xor(q1, 16, 64);
        q2 += __shfl_xor(q2, 16, 64);
        q3 += __shfl_xor(q3, 16, 64);
        // select this lane's row (msel = (lane>>3)&3)
        const int msel = (lane >> 3) & 3;
        const float v = (msel & 2) ? ((msel & 1) ? q3 : q2)
                                   : ((msel & 1) ? q1 : q0);
        const float z = fmaf(xrow[t], wih, v + bias);
        const float h = fast_tanh(z);
        reinterpret_cast<unsigned short*>(&hbuf[par ^ 1][w * 144])[hslot] =
            __builtin_bit_cast(unsigned short, (_Float16)h);
        if (t == TT - 1) out[64 + b * HH + jp] = h;
        __syncthreads();   // the ONLY barrier per step
    }

    // ---- epilogue: wave 0 computes out[b] = h_last . W_out + b_out ----
    if (w == 0) {   // final h is in parity 0 buffer
        const uint4 hv = *reinterpret_cast<const uint4*>(
            &hbuf[0][(lane >> 3) * 144 + (lane & 7) * 16]);   // rows 8l..8l+7
        const float4 w0 = reinterpret_cast<const float4*>(W_out)[2 * lane + 0];
        const float4 w1 = reinterpret_cast<const float4*>(W_out)[2 * lane + 1];
        float s = 0.f; __half2 p;
        p = __builtin_bit_cast(__half2, hv.x);
        s = fmaf(__low2float(p), w0.x, s); s = fmaf(__high2float(p), w0.y, s);
        p = __builtin_bit_cast(__half2, hv.y);
        s = fmaf(__low2float(p), w0.z, s); s = fmaf(__high2float(p), w0.w, s);
        p = __builtin_bit_cast(__half2, hv.z);
        s = fmaf(__low2float(p), w1.x, s); s = fmaf(__high2float(p), w1.y, s);
        p = __builtin_bit_cast(__half2, hv.w);
        s = fmaf(__low2float(p), w1.z, s); s = fmaf(__high2float(p), w1.w, s);
#pragma unroll
        for (int off = 32; off; off >>= 1) s += __shfl_down(s, off, 64);
        if (lane == 0) out[b] = s + b_out[0];
    }
}

extern "C" void kernel_launch(void* const* d_in, const int* in_sizes, int n_in,
                              void* d_out, int out_size, void* d_ws, size_t ws_size,
                              hipStream_t stream) {
    const float* x     = (const float*)d_in[0];  // inputs [B,T,1]
    // d_in[1] = state (ignored; reference uses zero initial hidden state)
    const float* W_ih  = (const float*)d_in[2];
    const float* W_hh  = (const float*)d_in[3];
    const float* b_ih  = (const float*)d_in[4];
    const float* b_hh  = (const float*)d_in[5];
    const float* W_out = (const float*)d_in[6];
    const float* b_out = (const float*)d_in[7];

    uint4* wsT = (uint4*)d_ws;   // 8*512*16B = 64KB packed fp16 chunk-7 tails
    // (written by every block with identical values each call; self-read only)

    rnn_cu3<<<dim3(BB), dim3(512), 0, stream>>>(
        x, W_ih, W_hh, b_ih, b_hh, W_out, b_out, (float*)d_out, wsT);
}